// Round 5
// baseline (538.522 us; speedup 1.0000x reference)
//
#include <hip/hip_runtime.h>

#define DEVI __device__ __forceinline__

typedef __bf16 bf16x8 __attribute__((ext_vector_type(8)));
typedef float f32x4 __attribute__((ext_vector_type(4)));

#define WAIT_VM(n) asm volatile("s_waitcnt vmcnt(" #n ")" ::: "memory")
#define WAIT_LGKM(n) asm volatile("s_waitcnt lgkmcnt(" #n ")" ::: "memory")

// ---------- exact bf16 RNE helpers ----------
DEVI unsigned short f2bf(float f) {
  unsigned u = __float_as_uint(f);
  u = (u + 0x7FFFu + ((u >> 16) & 1u)) >> 16;
  return (unsigned short)u;
}
DEVI float bf2f(unsigned short h) { return __uint_as_float(((unsigned)h) << 16); }
DEVI float bf16r(float f) { return bf2f(f2bf(f)); }

// ---------- fast MXINT8 scale from block amax (amax normal, >0) ----------
DEVI void mx_scales(float amax, float& scale, float& inv) {
  unsigned eb = __float_as_uint(amax) & 0x7f800000u;
  scale = __uint_as_float(eb - (6u << 23));          // 2^(e-6)
  inv   = __uint_as_float((260u << 23) - eb);        // 2^(6-e)
}

DEVI unsigned short quantv(float v, float scale, float inv) {
  float qv = rintf(v * inv);                          // RNE, matches jnp.round
  qv = fminf(fmaxf(qv, -128.f), 127.f);
  return f2bf(qv * scale);                            // exact in bf16
}

DEVI void quant8(const float* h, float amax, unsigned short* q) {
  if (amax > 0.f) {
    float scale, inv;
    mx_scales(amax, scale, inv);
#pragma unroll
    for (int k = 0; k < 8; ++k) q[k] = quantv(h[k], scale, inv);
  } else {
#pragma unroll
    for (int k = 0; k < 8; ++k) q[k] = 0;
  }
}

// ---------- 16-lane (DPP row) max reduction on the VALU pipe ----------
template <int N>
DEVI float qmax_step(float x) {
  int y = __builtin_amdgcn_update_dpp(0, __float_as_int(x), 0x120 | N, 0xF, 0xF, true);
  return fmaxf(x, __int_as_float(y));
}
DEVI float quad_row_max(float x) {
  x = qmax_step<1>(x);
  x = qmax_step<2>(x);
  x = qmax_step<4>(x);
  x = qmax_step<8>(x);
  return x;
}

// ---------- async global->LDS 16B ----------
DEVI void gl2lds16(const void* g, void* l) {
  __builtin_amdgcn_global_load_lds(
      (__attribute__((address_space(1))) void*)const_cast<void*>(g),
      (__attribute__((address_space(3))) void*)l, 16, 0, 0);
}

DEVI uint4 pack8(const unsigned short* q) {
  uint4 o;
  o.x = (unsigned)q[0] | ((unsigned)q[1] << 16);
  o.y = (unsigned)q[2] | ((unsigned)q[3] << 16);
  o.z = (unsigned)q[4] | ((unsigned)q[5] << 16);
  o.w = (unsigned)q[6] | ((unsigned)q[7] << 16);
  return o;
}

// ---------- merged prep: W1 quant | W2 quant | LN+quant in ONE dispatch ----------
__global__ __launch_bounds__(256) void prep_k(const float* __restrict__ W1,
                                              const float* __restrict__ W2,
                                              const float* __restrict__ X,
                                              const float* __restrict__ lw,
                                              const float* __restrict__ lb,
                                              unsigned short* __restrict__ qW1,
                                              unsigned short* __restrict__ qW2,
                                              unsigned short* __restrict__ a1) {
  __shared__ float red[4];
  const int bid = blockIdx.x;
  const int t = threadIdx.x;
  if (bid < 16384) {
    const float* src = (bid < 8192) ? W1 : W2;
    unsigned short* dst = (bid < 8192) ? qW1 : qW2;
    size_t idx = (size_t)(bid & 8191) * 256 + t;   // 8 elems/thread
    float4 v0 = ((const float4*)src)[idx * 2];
    float4 v1 = ((const float4*)src)[idx * 2 + 1];
    float h[8] = {v0.x, v0.y, v0.z, v0.w, v1.x, v1.y, v1.z, v1.w};
    float amax = 0.f;
#pragma unroll
    for (int k = 0; k < 8; ++k) amax = fmaxf(amax, fabsf(h[k]));
    amax = fmaxf(amax, __shfl_xor(amax, 1));   // 4 consecutive lanes = one 32-block
    amax = fmaxf(amax, __shfl_xor(amax, 2));
    unsigned short q[8];
    quant8(h, amax, q);
    ((uint4*)dst)[idx] = pack8(q);
  } else {
    const int H = 2048;
    const int row = bid - 16384;
    const int lane = t & 63, wave = t >> 6;
    const float* xr = X + (size_t)row * H;
    float4 v0 = ((const float4*)xr)[2 * t];
    float4 v1 = ((const float4*)xr)[2 * t + 1];
    float x[8] = {bf16r(v0.x), bf16r(v0.y), bf16r(v0.z), bf16r(v0.w),
                  bf16r(v1.x), bf16r(v1.y), bf16r(v1.z), bf16r(v1.w)};
    float s = 0.f;
#pragma unroll
    for (int k = 0; k < 8; ++k) s += x[k];
#pragma unroll
    for (int o = 32; o; o >>= 1) s += __shfl_xor(s, o);
    if (lane == 0) red[wave] = s;
    __syncthreads();
    float mu = (red[0] + red[1] + red[2] + red[3]) * (1.0f / H);
    __syncthreads();
    float v = 0.f;
#pragma unroll
    for (int k = 0; k < 8; ++k) { float d = x[k] - mu; v += d * d; }
#pragma unroll
    for (int o = 32; o; o >>= 1) v += __shfl_xor(v, o);
    if (lane == 0) red[wave] = v;
    __syncthreads();
    float var = (red[0] + red[1] + red[2] + red[3]) * (1.0f / H);
    float rstd = 1.0f / sqrtf(var + 1e-5f);
    float h[8];
    float amax = 0.f;
#pragma unroll
    for (int k = 0; k < 8; ++k) {
      int col = t * 8 + k;
      h[k] = bf16r((x[k] - mu) * rstd * lw[col] + lb[col]);
      amax = fmaxf(amax, fabsf(h[k]));
    }
    amax = fmaxf(amax, __shfl_xor(amax, 1));
    amax = fmaxf(amax, __shfl_xor(amax, 2));
    unsigned short q[8];
    quant8(h, amax, q);
    ((uint4*)(a1 + (size_t)row * H))[t] = pack8(q);
  }
}

// ============================================================================
// GEMM1: 256x256 tile, BK=32, 512 thr = 8 waves (2M x 4N), per-wave 128x64.
// Pipeline with register read-ahead (the m201 counted-lgkm discipline):
//  - 4 LDS bufs (tile t in buf t&3), stage tile t+3 during tile t (A units in
//    ph1, B units in ph2). vmcnt placed BEFORE the ph1-end barrier so that the
//    ph2 reads of buf t+1 (issued after that barrier) see all waves' staging
//    landed (vmcnt is per-wave; barrier makes it collective).
//  - ph1: MFMA(mh0) on regs read last ph2; issues mh1 reads; lgkmcnt(4).
//    ph2: MFMA(mh1); issues NEXT tile's mh0+B reads; lgkmcnt(8).
//    Reads are serviced UNDER the MFMA cluster instead of draining before it.
//  - vmcnt slack >= 2 phases for every staged unit; never drains in steady
//    state (vmcnt(6) keeps t+2's 4 + t+3's A2 in flight).
// LDS swizzle = r3's measured-zero-conflict 64B-row layout: chunk c of row r
// at pos c^((r>>1)&3); read chunk quad^((lr>>1)&3); staging keeps LDS dest
// linear and inverse-swizzles the global source chunk.
// Epilogue: bf16(gelu(bf16(y+bias))) + fused DPP MX-quant -> bf16 [M,N].
// ============================================================================
__global__ __launch_bounds__(512, 2) void gemm1_k(const unsigned short* __restrict__ A,
                                                  const unsigned short* __restrict__ B,
                                                  const float* __restrict__ bias,
                                                  unsigned short* __restrict__ outp) {
  constexpr int K = 2048, N = 8192, NT = K / 32;
  __shared__ __align__(16) unsigned short As[4 * 8192];  // 64 KiB (4 x 256x32)
  __shared__ __align__(16) unsigned short Bs[4 * 8192];  // 64 KiB

  const int tid = threadIdx.x;
  const int lane = tid & 63;
  const int lr = lane & 15;
  const int quad = lane >> 4;
  const int wave = tid >> 6;
  const int wm = wave >> 2;          // 0..1
  const int wn = wave & 3;           // 0..3

  // XCD-bijective swizzle: 512 blocks -> 64 contiguous per XCD
  int lin = blockIdx.y * 32 + blockIdx.x;
  lin = (lin & 7) * 64 + (lin >> 3);
  const int m0 = (lin >> 5) * 256;
  const int n0 = (lin & 31) * 256;

  const int chq = quad ^ ((lr >> 1) & 3);
  const int aro = (wm * 128 + lr) * 32 + chq * 8;   // + mh*2048 + i*512
  const int bro = (wn * 64 + lr) * 32 + chq * 8;    // + j*512

  // staging: thread tid -> row (tid>>2) within a 128-row unit, pos tid&3;
  // global source chunk = pos ^ ((row>>1)&3) = (tid&3)^((tid>>3)&3)
  const int srow = tid >> 2;
  const int sch = (tid & 3) ^ ((tid >> 3) & 3);
  const size_t aoff = (size_t)(m0 + srow) * K + sch * 8;
  const size_t boff = (size_t)(n0 + srow) * K + sch * 8;
  const int lb = (tid & ~63) * 8;    // wave-uniform LDS base (ushorts)

  f32x4 acc[8][4];
#pragma unroll
  for (int i = 0; i < 8; ++i)
#pragma unroll
    for (int j = 0; j < 4; ++j) acc[i][j] = (f32x4){0.f, 0.f, 0.f, 0.f};

  bf16x8 af0[4], af1[4], bA[4], bB[4];

#define G1_STAGE_A(T) { int bf_ = (T) & 3;                                         \
    gl2lds16(A + aoff + (size_t)(T) * 32, As + bf_ * 8192 + lb);                   \
    gl2lds16(A + aoff + (size_t)128 * K + (size_t)(T) * 32, As + bf_ * 8192 + 4096 + lb); }
#define G1_STAGE_B(T) { int bf_ = (T) & 3;                                         \
    gl2lds16(B + boff + (size_t)(T) * 32, Bs + bf_ * 8192 + lb);                   \
    gl2lds16(B + boff + (size_t)128 * K + (size_t)(T) * 32, Bs + bf_ * 8192 + 4096 + lb); }

  // prologue: stage tiles 0..2; drain tile 0 (keep 1,2 in flight); pre-read buf0
#pragma unroll
  for (int pt = 0; pt < 3; ++pt) { G1_STAGE_A(pt); G1_STAGE_B(pt); }
  WAIT_VM(8);
  __builtin_amdgcn_s_barrier();
#pragma unroll
  for (int i = 0; i < 4; ++i) af0[i] = *(const bf16x8*)(As + aro + i * 512);
#pragma unroll
  for (int j = 0; j < 4; ++j) bA[j] = *(const bf16x8*)(Bs + bro + j * 512);

#define G1_TILE(T, BC, BN_) {                                                      \
    const unsigned short* Ab_ = As + ((T) & 3) * 8192;                             \
    const bool pf3 = (T) + 3 < NT, pf2 = (T) + 2 < NT, pf1 = (T) + 1 < NT;         \
    /* ph1: MFMA(mh0) on af0/BC; read af1(mh1); stage A of T+3 */                  \
    if (pf3) G1_STAGE_A((T) + 3);                                                  \
    _Pragma("unroll")                                                              \
    for (int i = 0; i < 4; ++i) af1[i] = *(const bf16x8*)(Ab_ + aro + 2048 + i * 512); \
    if (pf3) { WAIT_VM(6); } else if (pf2) { WAIT_VM(4); } else { WAIT_VM(0); }    \
    WAIT_LGKM(4);                                                                  \
    __builtin_amdgcn_sched_barrier(0);                                             \
    __builtin_amdgcn_s_setprio(1);                                                 \
    _Pragma("unroll")                                                              \
    for (int i = 0; i < 4; ++i)                                                    \
      _Pragma("unroll")                                                            \
      for (int j = 0; j < 4; ++j)                                                  \
        acc[i][j] = __builtin_amdgcn_mfma_f32_16x16x32_bf16(af0[i], BC[j], acc[i][j], 0, 0, 0); \
    __builtin_amdgcn_s_setprio(0);                                                 \
    __builtin_amdgcn_s_barrier();                                                  \
    /* ph2: MFMA(mh1) on af1/BC; read next tile's af0+BN_; stage B of T+3 */       \
    if (pf3) G1_STAGE_B((T) + 3);                                                  \
    if (pf1) {                                                                     \
      const unsigned short* An_ = As + (((T) + 1) & 3) * 8192;                     \
      const unsigned short* Bn_ = Bs + (((T) + 1) & 3) * 8192;                     \
      _Pragma("unroll")                                                            \
      for (int i = 0; i < 4; ++i) af0[i] = *(const bf16x8*)(An_ + aro + i * 512);  \
      _Pragma("unroll")                                                            \
      for (int j = 0; j < 4; ++j) BN_[j] = *(const bf16x8*)(Bn_ + bro + j * 512);  \
      WAIT_LGKM(8);                                                                \
    } else { WAIT_LGKM(0); }                                                       \
    __builtin_amdgcn_sched_barrier(0);                                             \
    __builtin_amdgcn_s_setprio(1);                                                 \
    _Pragma("unroll")                                                              \
    for (int i = 0; i < 4; ++i)                                                    \
      _Pragma("unroll")                                                            \
      for (int j = 0; j < 4; ++j)                                                  \
        acc[4 + i][j] = __builtin_amdgcn_mfma_f32_16x16x32_bf16(af1[i], BC[j], acc[4 + i][j], 0, 0, 0); \
    __builtin_amdgcn_s_setprio(0);                                                 \
    __builtin_amdgcn_s_barrier(); }

  for (int t = 0; t < NT; t += 2) {
    G1_TILE(t, bA, bB);
    G1_TILE(t + 1, bB, bA);
  }

  // epilogue: D mapping col = lane&15, row = quad*4 + reg [m89-verified]
#pragma unroll
  for (int i = 0; i < 8; ++i) {
#pragma unroll
    for (int r = 0; r < 4; ++r) {
      const int gm = m0 + wm * 128 + i * 16 + quad * 4 + r;
      float g[4];
#pragma unroll
      for (int j = 0; j < 4; ++j) {
        float tt = bf16r(acc[i][j][r] + bias[n0 + wn * 64 + j * 16 + lr]);
        float u = 0.7978845608028654f * (tt + 0.044715f * tt * tt * tt);
        g[j] = bf16r(0.5f * tt * (1.0f + tanhf(u)));
      }
      float a = quad_row_max(fmaxf(fabsf(g[0]), fabsf(g[1])));
      float b = quad_row_max(fmaxf(fabsf(g[2]), fabsf(g[3])));
      unsigned short q[4];
      if (a > 0.f) {
        float sc2, iv; mx_scales(a, sc2, iv);
        q[0] = quantv(g[0], sc2, iv); q[1] = quantv(g[1], sc2, iv);
      } else { q[0] = q[1] = 0; }
      if (b > 0.f) {
        float sc2, iv; mx_scales(b, sc2, iv);
        q[2] = quantv(g[2], sc2, iv); q[3] = quantv(g[3], sc2, iv);
      } else { q[2] = q[3] = 0; }
      unsigned short* orow = outp + (size_t)gm * N + n0 + wn * 64 + lr;
#pragma unroll
      for (int j = 0; j < 4; ++j) orow[j * 16] = q[j];
    }
  }
}

// ============================================================================
// GEMM2: 128x256 tile, BK=32, 8 waves (2M x 4N), per-wave 64x64, 256 blocks.
// 5-buf LDS ring (120 KiB), stage tile t+4 during tile t, ONE phase + ONE
// barrier per K-tile. Phase: {read buf t+1 operands (safe: prev phase's
// vmcnt->barrier drained them for ALL waves); stage t+4; vmcnt(6) (drains
// t+2 for next phase's reads, keeps t+3/t+4 in flight); lgkmcnt(8) (drains
// last phase's operands only -> this phase's reads serviced under MFMA);
// 16 MFMA; barrier}.
// Epilogue: out = bf16(bf16(resid) + bf16(y + bias)) -> float.
// ============================================================================
__global__ __launch_bounds__(512, 2) void gemm2_k(const unsigned short* __restrict__ A,
                                                  const unsigned short* __restrict__ B,
                                                  const float* __restrict__ bias,
                                                  const float* __restrict__ resid,
                                                  float* __restrict__ outp) {
  constexpr int K = 8192, N = 2048, NT = K / 32;
  __shared__ __align__(16) unsigned short As[5 * 4096];  // 40 KiB (5 x 128x32)
  __shared__ __align__(16) unsigned short Bs[5 * 8192];  // 80 KiB (5 x 256x32)

  const int tid = threadIdx.x;
  const int lane = tid & 63;
  const int lr = lane & 15;
  const int quad = lane >> 4;
  const int wave = tid >> 6;
  const int wm = wave >> 2;          // 0..1
  const int wn = wave & 3;           // 0..3

  // XCD-bijective swizzle: 256 blocks -> 32 contiguous per XCD
  int lin = blockIdx.y * 8 + blockIdx.x;
  lin = (lin & 7) * 32 + (lin >> 3);
  const int m0 = (lin >> 3) * 128;
  const int n0 = (lin & 7) * 256;

  const int chq = quad ^ ((lr >> 1) & 3);
  const int aro = (wm * 64 + lr) * 32 + chq * 8;    // + i*512
  const int bro = (wn * 64 + lr) * 32 + chq * 8;    // + j*512

  const int srow = tid >> 2;
  const int sch = (tid & 3) ^ ((tid >> 3) & 3);
  const size_t aoff = (size_t)(m0 + srow) * K + sch * 8;
  const size_t boff = (size_t)(n0 + srow) * K + sch * 8;
  const int lb = (tid & ~63) * 8;

  f32x4 acc[4][4];
#pragma unroll
  for (int i = 0; i < 4; ++i)
#pragma unroll
    for (int j = 0; j < 4; ++j) acc[i][j] = (f32x4){0.f, 0.f, 0.f, 0.f};

  bf16x8 afX[4], bX[4], afY[4], bY[4];

#define G2_STAGE(T) { int bf_ = (T) % 5;                                           \
    gl2lds16(A + aoff + (size_t)(T) * 32, As + bf_ * 4096 + lb);                   \
    gl2lds16(B + boff + (size_t)(T) * 32, Bs + bf_ * 8192 + lb);                   \
    gl2lds16(B + boff + (size_t)128 * K + (size_t)(T) * 32, Bs + bf_ * 8192 + 4096 + lb); }

  // prologue: stage tiles 0..3; drain tiles 0,1 (keep 2,3); pre-read buf0
#pragma unroll
  for (int pt = 0; pt < 4; ++pt) G2_STAGE(pt);
  WAIT_VM(6);
  __builtin_amdgcn_s_barrier();
#pragma unroll
  for (int i = 0; i < 4; ++i) afX[i] = *(const bf16x8*)(As + aro + i * 512);
#pragma unroll
  for (int j = 0; j < 4; ++j) bX[j] = *(const bf16x8*)(Bs + bro + j * 512);

#define G2_TILE(T, AC, BC, AN, BN_) {                                              \
    const bool pf4 = (T) + 4 < NT, pf3 = (T) + 3 < NT, pf1 = (T) + 1 < NT;         \
    if (pf1) {                                                                     \
      const unsigned short* An_ = As + (((T) + 1) % 5) * 4096;                     \
      const unsigned short* Bn_ = Bs + (((T) + 1) % 5) * 8192;                     \
      _Pragma("unroll")                                                            \
      for (int i = 0; i < 4; ++i) AN[i] = *(const bf16x8*)(An_ + aro + i * 512);   \
      _Pragma("unroll")                                                            \
      for (int j = 0; j < 4; ++j) BN_[j] = *(const bf16x8*)(Bn_ + bro + j * 512);  \
    }                                                                              \
    if (pf4) G2_STAGE((T) + 4);                                                    \
    if (pf4) { WAIT_VM(6); } else if (pf3) { WAIT_VM(3); } else { WAIT_VM(0); }    \
    if (pf1) { WAIT_LGKM(8); } else { WAIT_LGKM(0); }                              \
    __builtin_amdgcn_sched_barrier(0);                                             \
    __builtin_amdgcn_s_setprio(1);                                                 \
    _Pragma("unroll")                                                              \
    for (int i = 0; i < 4; ++i)                                                    \
      _Pragma("unroll")                                                            \
      for (int j = 0; j < 4; ++j)                                                  \
        acc[i][j] = __builtin_amdgcn_mfma_f32_16x16x32_bf16(AC[i], BC[j], acc[i][j], 0, 0, 0); \
    __builtin_amdgcn_s_setprio(0);                                                 \
    __builtin_amdgcn_s_barrier(); }

  for (int t = 0; t < NT; t += 2) {
    G2_TILE(t, afX, bX, afY, bY);
    G2_TILE(t + 1, afY, bY, afX, bX);
  }

  // epilogue
#pragma unroll
  for (int i = 0; i < 4; ++i) {
#pragma unroll
    for (int j = 0; j < 4; ++j) {
#pragma unroll
      for (int r = 0; r < 4; ++r) {
        int gm = m0 + wm * 64 + i * 16 + quad * 4 + r;
        int gn = n0 + wn * 64 + j * 16 + lr;
        float h = bf16r(acc[i][j][r] + bias[gn]);
        float rr = bf16r(resid[(size_t)gm * N + gn]);
        outp[(size_t)gm * N + gn] = bf16r(rr + h);
      }
    }
  }
}

extern "C" void kernel_launch(void* const* d_in, const int* in_sizes, int n_in,
                              void* d_out, int out_size, void* d_ws, size_t ws_size,
                              hipStream_t stream) {
  const float* inputs = (const float*)d_in[0];  // [2,2048,2048]
  const float* ln_w   = (const float*)d_in[1];  // [2048]
  const float* ln_b   = (const float*)d_in[2];  // [2048]
  const float* W1     = (const float*)d_in[3];  // [8192,2048]
  const float* b1     = (const float*)d_in[4];  // [8192]
  const float* W2     = (const float*)d_in[5];  // [2048,8192]
  const float* b2     = (const float*)d_in[6];  // [2048]
  float* out = (float*)d_out;                   // [2,2048,2048] fp32 (bf16-valued)
  char* ws = (char*)d_ws;
  (void)in_sizes; (void)n_in; (void)out_size; (void)ws_size;

  // workspace layout (144 MiB total)
  unsigned short* qW1  = (unsigned short*)(ws);                      // 32 MiB
  unsigned short* qW2  = (unsigned short*)(ws + (size_t)33554432);   // 32 MiB
  unsigned short* a1   = (unsigned short*)(ws + (size_t)67108864);   // 16 MiB [4096,2048]
  unsigned short* act2 = (unsigned short*)(ws + (size_t)83886080);   // 64 MiB [4096,8192]

  // 1. merged prep: quantize W1+W2 and LN+quant the activations (one dispatch)
  prep_k<<<20480, 256, 0, stream>>>(W1, W2, inputs, ln_w, ln_b, qW1, qW2, a1);

  // 2. GEMM1 + bias + gelu + fused MX quant (DPP) -> quantized bf16 [4096,8192]
  gemm1_k<<<dim3(8192 / 256, 4096 / 256), 512, 0, stream>>>(a1, qW1, b1, act2);

  // 3. GEMM2 [4096,8192] x [2048,8192]^T + bias + residual -> fp32 out
  gemm2_k<<<dim3(2048 / 256, 4096 / 128), 512, 0, stream>>>(act2, qW2, b2, inputs, out);
}

// Round 6
// 502.315 us; speedup vs baseline: 1.0721x; 1.0721x over previous
//
#include <hip/hip_runtime.h>

#define DEVI __device__ __forceinline__

typedef __bf16 bf16x8 __attribute__((ext_vector_type(8)));
typedef float f32x4 __attribute__((ext_vector_type(4)));
typedef float f32x16 __attribute__((ext_vector_type(16)));

// ---------- exact bf16 RNE helpers ----------
DEVI unsigned short f2bf(float f) {
  unsigned u = __float_as_uint(f);
  u = (u + 0x7FFFu + ((u >> 16) & 1u)) >> 16;
  return (unsigned short)u;
}
DEVI float bf2f(unsigned short h) { return __uint_as_float(((unsigned)h) << 16); }
DEVI float bf16r(float f) { return bf2f(f2bf(f)); }

// ---------- fast MXINT8 scale from block amax (amax normal, >0) ----------
DEVI void mx_scales(float amax, float& scale, float& inv) {
  unsigned eb = __float_as_uint(amax) & 0x7f800000u;
  scale = __uint_as_float(eb - (6u << 23));          // 2^(e-6)
  inv   = __uint_as_float((260u << 23) - eb);        // 2^(6-e)
}

DEVI unsigned short quantv(float v, float scale, float inv) {
  float qv = rintf(v * inv);                          // RNE, matches jnp.round
  qv = fminf(fmaxf(qv, -128.f), 127.f);
  return f2bf(qv * scale);                            // exact in bf16
}

DEVI void quant8(const float* h, float amax, unsigned short* q) {
  if (amax > 0.f) {
    float scale, inv;
    mx_scales(amax, scale, inv);
#pragma unroll
    for (int k = 0; k < 8; ++k) q[k] = quantv(h[k], scale, inv);
  } else {
#pragma unroll
    for (int k = 0; k < 8; ++k) q[k] = 0;
  }
}

// ---------- 16-lane (DPP row) max reduction on the VALU pipe ----------
template <int N>
DEVI float qmax_step(float x) {
  int y = __builtin_amdgcn_update_dpp(0, __float_as_int(x), 0x120 | N, 0xF, 0xF, true);
  return fmaxf(x, __int_as_float(y));
}
DEVI float quad_row_max(float x) {
  x = qmax_step<1>(x);
  x = qmax_step<2>(x);
  x = qmax_step<4>(x);
  x = qmax_step<8>(x);
  return x;
}

// ---------- async global->LDS 16B ----------
DEVI void gl2lds16(const void* g, void* l) {
  __builtin_amdgcn_global_load_lds(
      (__attribute__((address_space(1))) void*)const_cast<void*>(g),
      (__attribute__((address_space(3))) void*)l, 16, 0, 0);
}

DEVI uint4 pack8(const unsigned short* q) {
  uint4 o;
  o.x = (unsigned)q[0] | ((unsigned)q[1] << 16);
  o.y = (unsigned)q[2] | ((unsigned)q[3] << 16);
  o.z = (unsigned)q[4] | ((unsigned)q[5] << 16);
  o.w = (unsigned)q[6] | ((unsigned)q[7] << 16);
  return o;
}

// ---------- merged prep: W1 quant | W2 quant | LN+quant in ONE dispatch ----------
__global__ __launch_bounds__(256) void prep_k(const float* __restrict__ W1,
                                              const float* __restrict__ W2,
                                              const float* __restrict__ X,
                                              const float* __restrict__ lw,
                                              const float* __restrict__ lb,
                                              unsigned short* __restrict__ qW1,
                                              unsigned short* __restrict__ qW2,
                                              unsigned short* __restrict__ a1) {
  __shared__ float red[4];
  const int bid = blockIdx.x;
  const int t = threadIdx.x;
  if (bid < 16384) {
    const float* src = (bid < 8192) ? W1 : W2;
    unsigned short* dst = (bid < 8192) ? qW1 : qW2;
    size_t idx = (size_t)(bid & 8191) * 256 + t;   // 8 elems/thread
    float4 v0 = ((const float4*)src)[idx * 2];
    float4 v1 = ((const float4*)src)[idx * 2 + 1];
    float h[8] = {v0.x, v0.y, v0.z, v0.w, v1.x, v1.y, v1.z, v1.w};
    float amax = 0.f;
#pragma unroll
    for (int k = 0; k < 8; ++k) amax = fmaxf(amax, fabsf(h[k]));
    amax = fmaxf(amax, __shfl_xor(amax, 1));   // 4 consecutive lanes = one 32-block
    amax = fmaxf(amax, __shfl_xor(amax, 2));
    unsigned short q[8];
    quant8(h, amax, q);
    ((uint4*)dst)[idx] = pack8(q);
  } else {
    const int H = 2048;
    const int row = bid - 16384;
    const int lane = t & 63, wave = t >> 6;
    const float* xr = X + (size_t)row * H;
    float4 v0 = ((const float4*)xr)[2 * t];
    float4 v1 = ((const float4*)xr)[2 * t + 1];
    float x[8] = {bf16r(v0.x), bf16r(v0.y), bf16r(v0.z), bf16r(v0.w),
                  bf16r(v1.x), bf16r(v1.y), bf16r(v1.z), bf16r(v1.w)};
    float s = 0.f;
#pragma unroll
    for (int k = 0; k < 8; ++k) s += x[k];
#pragma unroll
    for (int o = 32; o; o >>= 1) s += __shfl_xor(s, o);
    if (lane == 0) red[wave] = s;
    __syncthreads();
    float mu = (red[0] + red[1] + red[2] + red[3]) * (1.0f / H);
    __syncthreads();
    float v = 0.f;
#pragma unroll
    for (int k = 0; k < 8; ++k) { float d = x[k] - mu; v += d * d; }
#pragma unroll
    for (int o = 32; o; o >>= 1) v += __shfl_xor(v, o);
    if (lane == 0) red[wave] = v;
    __syncthreads();
    float var = (red[0] + red[1] + red[2] + red[3]) * (1.0f / H);
    float rstd = 1.0f / sqrtf(var + 1e-5f);
    float h[8];
    float amax = 0.f;
#pragma unroll
    for (int k = 0; k < 8; ++k) {
      int col = t * 8 + k;
      h[k] = bf16r((x[k] - mu) * rstd * lw[col] + lb[col]);
      amax = fmaxf(amax, fabsf(h[k]));
    }
    amax = fmaxf(amax, __shfl_xor(amax, 1));
    amax = fmaxf(amax, __shfl_xor(amax, 2));
    unsigned short q[8];
    quant8(h, amax, q);
    ((uint4*)(a1 + (size_t)row * H))[t] = pack8(q);
  }
}

// ---------- GEMM: C[m,n] = sum_k A[m,k]*B[n,k], A/B bf16, fp32 acc ----------
// ROUND-0 STRUCTURE (measured best: 187.7us, 0 bank conflicts), with MFMA
// shape switched 16x16x32 -> 32x32x16 and LDS-read addresses hoisted:
//  - 128x128 tile, BK=64, 4 waves (2x2), per-wave 64x64 = 2x2 of 32x32x16.
//  - Per K-tile per wave: 16 ds_read_b128 (unchanged) but 16 MFMA (was 32)
//    and ~zero in-loop address VALU (posh[] table precomputed). Mechanism:
//    r0 was VALU/issue-bound (VALUBusy 70% >> MfmaUtil 33%).
//  - LDS layout identical to r0: row 64 ushorts (128 B), chunk c of row r at
//    pos c^(r&7); staging linear dest + inverse-swizzled global source.
//    32x32 operand: lane l reads row l&31, k-chunk kk*2+(l>>5) -> pos =
//    (kk*2+(l>>5))^(l&7); bank = 4*pos, pos uniform over 0..7 -> conflict-free.
//  - D layout [m74/m101]: col = lane&31, row = (reg&3)+8*(reg>>2)+4*(lane>>5).
// MODE 1: h = bf16(gelu_tanh(bf16(y+bias))), fused MX-quant: one 32x32 frag
//   row = one MX 32-block -> quad_row_max + shfl_xor(16) amax -> bf16 [M,N].
// MODE 2: out = bf16(bf16(resid) + bf16(y + bias)) -> float [M,N]
template <int MODE>
__global__ __launch_bounds__(256) void gemm_mx(const unsigned short* __restrict__ A,
                                               const unsigned short* __restrict__ B,
                                               int M, int N, int K,
                                               const float* __restrict__ bias,
                                               const float* __restrict__ resid,
                                               void* __restrict__ outp) {
  __shared__ unsigned short As[128 * 64];
  __shared__ unsigned short Bs[128 * 64];

  const int tid = threadIdx.x;
  const int lane = tid & 63;
  const int wave = tid >> 6;
  const int wr = (wave >> 1) * 64;   // wave row offset in tile
  const int wc = (wave & 1) * 64;    // wave col offset in tile
  const int l31 = lane & 31;
  const int hi = lane >> 5;
  const int l7 = lane & 7;

  const int m0 = blockIdx.y * 128;
  const int n0 = blockIdx.x * 128;

  // staging: LDS unit n (fixed dest n*16 B) = row n>>3, LDS chunk n&7.
  // Source global chunk = (n&7) ^ (row&7)  [swizzle].  (identical to r0)
  size_t aoff[4], boff[4];
  int lbase[4];
#pragma unroll
  for (int j = 0; j < 4; ++j) {
    int n = j * 256 + tid;
    int r = n >> 3, c = (n & 7) ^ (r & 7);
    aoff[j] = (size_t)(m0 + r) * K + (size_t)c * 8;
    boff[j] = (size_t)(n0 + r) * K + (size_t)c * 8;
    lbase[j] = (j * 256 + (tid & ~63)) * 8;  // wave-uniform LDS base (ushort units)
  }

  // hoisted fragment-read addressing (ushort units, loop-invariant)
  int posh[4];
#pragma unroll
  for (int kk = 0; kk < 4; ++kk) posh[kk] = ((kk * 2 + hi) ^ l7) * 8;
  int aBase[2], bBase[2];
#pragma unroll
  for (int mi = 0; mi < 2; ++mi) aBase[mi] = (wr + mi * 32 + l31) * 64;
#pragma unroll
  for (int nj = 0; nj < 2; ++nj) bBase[nj] = (wc + nj * 32 + l31) * 64;

  f32x16 acc[2][2];
#pragma unroll
  for (int i = 0; i < 2; ++i)
#pragma unroll
    for (int j = 0; j < 2; ++j)
#pragma unroll
      for (int k = 0; k < 16; ++k) acc[i][j][k] = 0.f;

  for (int k0 = 0; k0 < K; k0 += 64) {
#pragma unroll
    for (int j = 0; j < 4; ++j) gl2lds16(A + aoff[j] + k0, As + lbase[j]);
#pragma unroll
    for (int j = 0; j < 4; ++j) gl2lds16(B + boff[j] + k0, Bs + lbase[j]);
    __syncthreads();  // drains vmcnt -> LDS tiles visible
#pragma unroll
    for (int kk = 0; kk < 4; ++kk) {
      bf16x8 a2[2], b2[2];
#pragma unroll
      for (int mi = 0; mi < 2; ++mi) a2[mi] = *(const bf16x8*)(As + aBase[mi] + posh[kk]);
#pragma unroll
      for (int nj = 0; nj < 2; ++nj) b2[nj] = *(const bf16x8*)(Bs + bBase[nj] + posh[kk]);
#pragma unroll
      for (int mi = 0; mi < 2; ++mi)
#pragma unroll
        for (int nj = 0; nj < 2; ++nj)
          acc[mi][nj] = __builtin_amdgcn_mfma_f32_32x32x16_bf16(a2[mi], b2[nj], acc[mi][nj], 0, 0, 0);
    }
    __syncthreads();  // all reads done before next stage overwrites
  }

  // epilogue: D mapping col = lane&31, row = (reg&3)+8*(reg>>2)+4*hi [m74/m101]
  if (MODE == 1) {
#pragma unroll
    for (int mi = 0; mi < 2; ++mi) {
#pragma unroll
      for (int nj = 0; nj < 2; ++nj) {
        const int gnb = n0 + wc + nj * 32 + l31;
        const float bv = bias[gnb];
        unsigned short* ocol = (unsigned short*)outp + gnb;
        const f32x16 v = acc[mi][nj];
#pragma unroll
        for (int k = 0; k < 16; ++k) {
          const int gm = m0 + wr + mi * 32 + (k & 3) + 8 * (k >> 2) + 4 * hi;
          float tt = bf16r(v[k] + bv);
          float u = 0.7978845608028654f * (tt + 0.044715f * tt * tt * tt);
          float g = bf16r(0.5f * tt * (1.0f + tanhf(u)));
          // MX block = this frag row (32 cols) = the 32 lanes of this half
          float am = quad_row_max(fabsf(g));
          am = fmaxf(am, __shfl_xor(am, 16));
          unsigned short q = 0;
          if (am > 0.f) {
            float sc2, iv; mx_scales(am, sc2, iv);
            q = quantv(g, sc2, iv);
          }
          ocol[(size_t)gm * N] = q;
        }
      }
    }
  } else {
#pragma unroll
    for (int mi = 0; mi < 2; ++mi) {
#pragma unroll
      for (int nj = 0; nj < 2; ++nj) {
        const int gnb = n0 + wc + nj * 32 + l31;
        const float bv = bias[gnb];
        const f32x16 v = acc[mi][nj];
#pragma unroll
        for (int k = 0; k < 16; ++k) {
          const int gm = m0 + wr + mi * 32 + (k & 3) + 8 * (k >> 2) + 4 * hi;
          float h = bf16r(v[k] + bv);
          float rr = bf16r(resid[(size_t)gm * N + gnb]);
          ((float*)outp)[(size_t)gm * N + gnb] = bf16r(rr + h);
        }
      }
    }
  }
  (void)M;
}

extern "C" void kernel_launch(void* const* d_in, const int* in_sizes, int n_in,
                              void* d_out, int out_size, void* d_ws, size_t ws_size,
                              hipStream_t stream) {
  const float* inputs = (const float*)d_in[0];  // [2,2048,2048]
  const float* ln_w   = (const float*)d_in[1];  // [2048]
  const float* ln_b   = (const float*)d_in[2];  // [2048]
  const float* W1     = (const float*)d_in[3];  // [8192,2048]
  const float* b1     = (const float*)d_in[4];  // [8192]
  const float* W2     = (const float*)d_in[5];  // [2048,8192]
  const float* b2     = (const float*)d_in[6];  // [2048]
  float* out = (float*)d_out;                   // [2,2048,2048] fp32 (bf16-valued)
  char* ws = (char*)d_ws;
  (void)in_sizes; (void)n_in; (void)out_size; (void)ws_size;

  // workspace layout (144 MiB total)
  unsigned short* qW1  = (unsigned short*)(ws);                      // 32 MiB
  unsigned short* qW2  = (unsigned short*)(ws + (size_t)33554432);   // 32 MiB
  unsigned short* a1   = (unsigned short*)(ws + (size_t)67108864);   // 16 MiB [4096,2048]
  unsigned short* act2 = (unsigned short*)(ws + (size_t)83886080);   // 64 MiB [4096,8192]

  const int M = 4096;

  // 1. merged prep: quantize W1+W2 and LN+quant the activations (one dispatch)
  prep_k<<<20480, 256, 0, stream>>>(W1, W2, inputs, ln_w, ln_b, qW1, qW2, a1);

  // 2. GEMM1 + bias + gelu + fused MX quant (DPP) -> quantized bf16 [4096,8192]
  gemm_mx<1><<<dim3(8192 / 128, M / 128), 256, 0, stream>>>(
      a1, qW1, M, 8192, 2048, b1, nullptr, (void*)act2);

  // 3. GEMM2 [4096,8192] x [2048,8192]^T + bias + residual -> fp32 out
  gemm_mx<2><<<dim3(2048 / 128, M / 128), 256, 0, stream>>>(
      act2, qW2, M, 2048, 8192, b2, inputs, (void*)out);
}